// Round 3
// baseline (263.490 us; speedup 1.0000x reference)
//
#include <hip/hip_runtime.h>
#include <hip/hip_bf16.h>

#define S_LEN 2048
#define NHEADS 32
#define NKV 8
#define HD 128
#define QK_SCALE 0.08838834764831845f   // 1/sqrt(128)
#define LOG2E 1.4426950408889634f

#define BQ 64                 // q rows per block
#define BK 32                 // kv rows per tile
#define NQT (S_LEN / BQ)      // 32 q tiles
#define QSTR (NHEADS * HD)    // 4096
#define KSTR (NKV * HD)       // 1024
#define CH 512                // target kv rows per chunk (split-KV)
#define MAXC 4                // max chunks per (h,qt)

#define K_STRIDE 136          // LDS row stride (shorts)
#define VT_STRIDE 40
#define P_STRIDE 40

#define SLOT_ACC 8192                       // shorts per partial slot (64*128)
#define NSLOT (NQT * NHEADS * MAXC)         // 4096

typedef __attribute__((ext_vector_type(8))) short bf16x8;
typedef __attribute__((ext_vector_type(4))) float f32x4;
typedef __attribute__((ext_vector_type(4))) unsigned u32x4;

__device__ inline unsigned cvt_pk_bf16(float lo, float hi) {
    unsigned r;
    asm("v_cvt_pk_bf16_f32 %0, %1, %2" : "=v"(r) : "v"(lo), "v"(hi));
    return r;
}
__device__ inline short f2bf(float f) {
    unsigned u = __float_as_uint(f);
    u += 0x7fffu + ((u >> 16) & 1u);
    return (short)(u >> 16);
}
__device__ inline float bf2f(short s) {
    return __uint_as_float(((unsigned)(unsigned short)s) << 16);
}
__device__ inline bf16x8 as_bf16x8(u32x4 v) {
    union { u32x4 u; bf16x8 b; } c; c.u = v; return c.b;
}

// Shared between pass1 and combine: chunk decomposition of the live KV range.
// live = [kb_start(ALiBi), kv_end(causal)); nu balanced chunks rounded to BK.
__device__ inline void chunk_range(int qt, float slope, int split_ok, int c,
                                   int& kb0, int& kb1, int& nu) {
    int kv_end = qt * BQ + BQ;
    float thresh = (float)(qt * BQ) - 31.0f - 45.0f / slope;
    int t = (int)floorf(thresh);
    int kb_start = (t < 0) ? 0 : (((t >> 5) + 1) << 5);
    int live = kv_end - kb_start;
    nu = split_ok ? ((live + CH - 1) / CH) : 1;
    int clen = (live + nu - 1) / nu;
    clen = ((clen + 31) >> 5) << 5;
    kb0 = kb_start + c * clen;
    int e = kb0 + clen;
    kb1 = (e < kv_end) ? e : kv_end;
}

__global__ __launch_bounds__(256) void attn_fwd(
    const float* __restrict__ Q, const float* __restrict__ K,
    const float* __restrict__ V, const float* __restrict__ SL,
    float* __restrict__ O, short* __restrict__ ws_acc,
    float* __restrict__ ws_ml, int split_ok)
{
    const int bx   = blockIdx.x;
    const int c    = bx & 3;
    const int h    = (bx >> 2) & (NHEADS - 1);
    const int qt   = (NQT - 1) - (bx >> 7);     // heavy q-tiles dispatch first
    const int kvh  = h >> 2;
    const float slope = SL[h];

    int kb0, kb1, nu;
    chunk_range(qt, slope, split_ok, c, kb0, kb1, nu);
    if (c >= nu) return;                         // empty chunk (block-uniform)

    const int tid  = threadIdx.x;
    const int w    = tid >> 6;
    const int lane = tid & 63;
    const int l16  = lane & 15;
    const int lq   = lane >> 4;

    __shared__ short Ks[BK * K_STRIDE];
    __shared__ short VTs[HD * VT_STRIDE];
    __shared__ short Ps[4][16 * P_STRIDE];

    const int qrow0 = qt * BQ + w * 16;

    // ---- Q fragments ----
    bf16x8 qf[4];
    {
        const float* qp = Q + (size_t)(qrow0 + l16) * QSTR + h * HD + lq * 8;
        #pragma unroll
        for (int d0 = 0; d0 < 4; ++d0) {
            f32x4 a = *(const f32x4*)(qp + d0 * 32);
            f32x4 b = *(const f32x4*)(qp + d0 * 32 + 4);
            u32x4 t;
            t[0] = cvt_pk_bf16(a[0], a[1]); t[1] = cvt_pk_bf16(a[2], a[3]);
            t[2] = cvt_pk_bf16(b[0], b[1]); t[3] = cvt_pk_bf16(b[2], b[3]);
            qf[d0] = as_bf16x8(t);
        }
    }

    f32x4 acc[8];
    #pragma unroll
    for (int t = 0; t < 8; ++t) acc[t] = (f32x4){0.f, 0.f, 0.f, 0.f};
    float m_i[4] = {-1e30f, -1e30f, -1e30f, -1e30f};
    float l_i[4] = {0.f, 0.f, 0.f, 0.f};

    // ---- staging thread mapping ----
    const int sr  = tid >> 4, scc = tid & 15;
    const int vd  = tid & 127, vrb = (tid >> 7) * 8;
    const float* Kbase = K + (size_t)kvh * HD + scc * 8;
    const float* Vbase = V + (size_t)kvh * HD + vd;

    float kr[2][8], vr[2][8];

    auto load_regs = [&](int kb) {
        #pragma unroll
        for (int s = 0; s < 2; ++s) {
            const float* kp = Kbase + (size_t)(kb + sr + s * 16) * KSTR;
            *(f32x4*)&kr[s][0] = *(const f32x4*)kp;
            *(f32x4*)&kr[s][4] = *(const f32x4*)(kp + 4);
        }
        #pragma unroll
        for (int s = 0; s < 2; ++s)
            #pragma unroll
            for (int j = 0; j < 8; ++j)
                vr[s][j] = Vbase[(size_t)(kb + vrb + s * 16 + j) * KSTR];
    };

    auto store_tile = [&]() {
        #pragma unroll
        for (int s = 0; s < 2; ++s) {
            u32x4 t;
            t[0] = cvt_pk_bf16(kr[s][0], kr[s][1]);
            t[1] = cvt_pk_bf16(kr[s][2], kr[s][3]);
            t[2] = cvt_pk_bf16(kr[s][4], kr[s][5]);
            t[3] = cvt_pk_bf16(kr[s][6], kr[s][7]);
            *(u32x4*)&Ks[(sr + s * 16) * K_STRIDE + scc * 8] = t;
        }
        #pragma unroll
        for (int s = 0; s < 2; ++s) {
            u32x4 t;
            t[0] = cvt_pk_bf16(vr[s][0], vr[s][1]);
            t[1] = cvt_pk_bf16(vr[s][2], vr[s][3]);
            t[2] = cvt_pk_bf16(vr[s][4], vr[s][5]);
            t[3] = cvt_pk_bf16(vr[s][6], vr[s][7]);
            *(u32x4*)&VTs[vd * VT_STRIDE + vrb + s * 16] = t;
        }
    };

    load_regs(kb0);

    for (int kb = kb0; kb < kb1; kb += BK) {
        __syncthreads();
        store_tile();
        __syncthreads();
        if (kb + BK < kb1) load_regs(kb + BK);

        const bool live = (kb <= qrow0 + 15) &&
                          (slope * (float)(qrow0 - kb - 31) < 45.0f);
        if (live) {
            // ---- QK^T ----
            f32x4 sc0 = (f32x4){0.f,0.f,0.f,0.f};
            f32x4 sc1 = (f32x4){0.f,0.f,0.f,0.f};
            __builtin_amdgcn_s_setprio(1);
            #pragma unroll
            for (int d0 = 0; d0 < 4; ++d0) {
                bf16x8 kf0 = *(const bf16x8*)&Ks[l16 * K_STRIDE + d0 * 32 + lq * 8];
                bf16x8 kf1 = *(const bf16x8*)&Ks[(16 + l16) * K_STRIDE + d0 * 32 + lq * 8];
                sc0 = __builtin_amdgcn_mfma_f32_16x16x32_bf16(qf[d0], kf0, sc0, 0, 0, 0);
                sc1 = __builtin_amdgcn_mfma_f32_16x16x32_bf16(qf[d0], kf1, sc1, 0, 0, 0);
            }
            __builtin_amdgcn_s_setprio(0);

            // ---- scale + ALiBi + causal + online softmax (defer-max) ----
            float p0v[4], p1v[4];
            #pragma unroll
            for (int i = 0; i < 4; ++i) {
                const int qrow = qrow0 + 4 * lq + i;
                const int kc0 = kb + l16;
                const int kc1 = kb + 16 + l16;
                float s0 = (kc0 > qrow) ? -1e30f
                         : sc0[i] * QK_SCALE + slope * (float)(kc0 - qrow);
                float s1 = (kc1 > qrow) ? -1e30f
                         : sc1[i] * QK_SCALE + slope * (float)(kc1 - qrow);

                float rm = fmaxf(s0, s1);
                rm = fmaxf(rm, __shfl_xor(rm, 1));
                rm = fmaxf(rm, __shfl_xor(rm, 2));
                rm = fmaxf(rm, __shfl_xor(rm, 4));
                rm = fmaxf(rm, __shfl_xor(rm, 8));

                if (rm > m_i[i] + 8.0f) {
                    float alpha = exp2f((m_i[i] - rm) * LOG2E);
                    m_i[i] = rm;
                    l_i[i] *= alpha;
                    #pragma unroll
                    for (int t = 0; t < 8; ++t) acc[t][i] *= alpha;
                }
                float p0 = exp2f((s0 - m_i[i]) * LOG2E);
                float p1 = exp2f((s1 - m_i[i]) * LOG2E);
                p0v[i] = p0; p1v[i] = p1;

                float ps = p0 + p1;
                ps += __shfl_xor(ps, 1);
                ps += __shfl_xor(ps, 2);
                ps += __shfl_xor(ps, 4);
                ps += __shfl_xor(ps, 8);
                l_i[i] += ps;
            }

            // ---- P -> LDS -> A-fragment ----
            short* PsW = &Ps[w][0];
            #pragma unroll
            for (int i = 0; i < 4; ++i) {
                PsW[(4 * lq + i) * P_STRIDE + l16]      = f2bf(p0v[i]);
                PsW[(4 * lq + i) * P_STRIDE + 16 + l16] = f2bf(p1v[i]);
            }
            asm volatile("s_waitcnt lgkmcnt(0)" ::: "memory");
            bf16x8 pf = *(const bf16x8*)&PsW[l16 * P_STRIDE + lq * 8];

            // ---- PV ----
            __builtin_amdgcn_s_setprio(1);
            #pragma unroll
            for (int nt = 0; nt < 8; ++nt) {
                bf16x8 vf = *(const bf16x8*)&VTs[(nt * 16 + l16) * VT_STRIDE + lq * 8];
                acc[nt] = __builtin_amdgcn_mfma_f32_16x16x32_bf16(pf, vf, acc[nt], 0, 0, 0);
            }
            __builtin_amdgcn_s_setprio(0);
        }
    }

    if (nu == 1) {
        // ---- direct epilogue ----
        #pragma unroll
        for (int i = 0; i < 4; ++i) {
            float rl = 1.0f / l_i[i];
            const size_t row = (size_t)(qrow0 + 4 * lq + i);
            float* op = O + row * QSTR + h * HD + l16;
            #pragma unroll
            for (int nt = 0; nt < 8; ++nt)
                op[nt * 16] = acc[nt][i] * rl;
        }
    } else {
        // ---- partial epilogue: raw acc (bf16) + m,l (f32) to ws ----
        const int slot = (qt * NHEADS + h) * MAXC + c;
        short* pa = ws_acc + (size_t)slot * SLOT_ACC;
        float* ml = ws_ml + (size_t)slot * (BQ * 2);
        #pragma unroll
        for (int i = 0; i < 4; ++i) {
            const int rl_ = w * 16 + 4 * lq + i;
            #pragma unroll
            for (int nt = 0; nt < 8; ++nt)
                pa[rl_ * HD + nt * 16 + l16] = f2bf(acc[nt][i]);
            if (l16 == 0) {
                ml[rl_ * 2]     = m_i[i];
                ml[rl_ * 2 + 1] = l_i[i];
            }
        }
    }
}

__global__ __launch_bounds__(256) void attn_combine(
    const float* __restrict__ SL, const short* __restrict__ ws_acc,
    const float* __restrict__ ws_ml, float* __restrict__ O)
{
    const int bx = blockIdx.x;
    const int qt = bx >> 5;
    const int h  = bx & (NHEADS - 1);
    const float slope = SL[h];

    int kb0, kb1, nu;
    chunk_range(qt, slope, 1, 0, kb0, kb1, nu);
    if (nu <= 1) return;                       // pass 1 wrote O directly

    const int tid = threadIdx.x;
    const int r   = tid >> 2;                  // row 0..63
    const int db  = tid & 3;                   // 32-d block

    const int slot0 = (qt * NHEADS + h) * MAXC;

    float m_c[MAXC], l_c[MAXC];
    float M = -1e30f;
    #pragma unroll
    for (int c = 0; c < MAXC; ++c) {
        if (c >= nu) break;
        const float* ml = ws_ml + (size_t)(slot0 + c) * (BQ * 2) + r * 2;
        m_c[c] = ml[0];
        l_c[c] = ml[1];
        M = fmaxf(M, m_c[c]);
    }

    float o[32];
    #pragma unroll
    for (int j = 0; j < 32; ++j) o[j] = 0.f;
    float wsum = 0.f;

    #pragma unroll
    for (int c = 0; c < MAXC; ++c) {
        if (c >= nu) break;
        float wgt = exp2f((m_c[c] - M) * LOG2E);
        wsum += wgt * l_c[c];
        const short* pa = ws_acc + (size_t)(slot0 + c) * SLOT_ACC + r * HD + db * 32;
        #pragma unroll
        for (int jv = 0; jv < 4; ++jv) {
            bf16x8 v8 = *(const bf16x8*)(pa + jv * 8);
            #pragma unroll
            for (int j = 0; j < 8; ++j)
                o[jv * 8 + j] += wgt * bf2f(v8[j]);
        }
    }

    float inv = 1.0f / wsum;
    float* op = O + (size_t)(qt * BQ + r) * QSTR + h * HD + db * 32;
    #pragma unroll
    for (int j = 0; j < 32; ++j) op[j] = o[j] * inv;
}

extern "C" void kernel_launch(void* const* d_in, const int* in_sizes, int n_in,
                              void* d_out, int out_size, void* d_ws, size_t ws_size,
                              hipStream_t stream) {
    const float* Q  = (const float*)d_in[0];
    const float* K  = (const float*)d_in[1];
    const float* V  = (const float*)d_in[2];
    const float* SL = (const float*)d_in[3];
    float* O = (float*)d_out;

    const size_t needed = (size_t)NSLOT * SLOT_ACC * sizeof(short)
                        + (size_t)NSLOT * BQ * 2 * sizeof(float);
    const int split_ok = (d_ws != nullptr && ws_size >= needed) ? 1 : 0;
    short* ws_acc = (short*)d_ws;
    float* ws_ml  = (float*)((char*)d_ws + (size_t)NSLOT * SLOT_ACC * sizeof(short));

    attn_fwd<<<dim3(NQT * NHEADS * MAXC), dim3(256), 0, stream>>>(
        Q, K, V, SL, O, ws_acc, ws_ml, split_ok);
    if (split_ok)
        attn_combine<<<dim3(NQT * NHEADS), dim3(256), 0, stream>>>(
            SL, ws_acc, ws_ml, O);
}

// Round 4
// 159.036 us; speedup vs baseline: 1.6568x; 1.6568x over previous
//
#include <hip/hip_runtime.h>
#include <hip/hip_bf16.h>

#define S_LEN 2048
#define NHEADS 32
#define NKV 8
#define HD 128
#define QK_SCALE 0.08838834764831845f   // 1/sqrt(128)
#define LOG2E 1.4426950408889634f

#define BQ 64                 // q rows per block
#define BK 32                 // kv rows per tile
#define NQT (S_LEN / BQ)      // 32 q tiles
#define QSTR (NHEADS * HD)    // 4096
#define KSTR (NKV * HD)       // 1024

#define K_STRIDE 136          // LDS row stride (shorts)
#define VT_STRIDE 40
#define P_STRIDE 40

typedef __attribute__((ext_vector_type(8))) short bf16x8;
typedef __attribute__((ext_vector_type(4))) float f32x4;
typedef __attribute__((ext_vector_type(4))) unsigned u32x4;

__device__ inline unsigned cvt_pk_bf16(float lo, float hi) {
    unsigned r;
    asm("v_cvt_pk_bf16_f32 %0, %1, %2" : "=v"(r) : "v"(lo), "v"(hi));
    return r;
}
__device__ inline short f2bf(float f) {
    unsigned u = __float_as_uint(f);
    u += 0x7fffu + ((u >> 16) & 1u);
    return (short)(u >> 16);
}
__device__ inline bf16x8 as_bf16x8(u32x4 v) {
    union { u32x4 u; bf16x8 b; } c; c.u = v; return c.b;
}

__global__ __launch_bounds__(256) void attn_fwd(
    const float* __restrict__ Q, const float* __restrict__ K,
    const float* __restrict__ V, const float* __restrict__ SL,
    float* __restrict__ O)
{
    const int bx   = blockIdx.x;
    const int h    = bx & (NHEADS - 1);
    const int qt   = (NQT - 1) - (bx >> 5);     // heavy q-tiles dispatch first
    const int kvh  = h >> 2;
    const float slope = SL[h];

    const int tid  = threadIdx.x;
    const int w    = tid >> 6;
    const int lane = tid & 63;
    const int l16  = lane & 15;
    const int lq   = lane >> 4;

    __shared__ short Ks[2][BK * K_STRIDE];     // double-buffered K [k][d]
    __shared__ short VTs[2][HD * VT_STRIDE];   // double-buffered V^T [d][k]
    __shared__ short Ps[4][16 * P_STRIDE];     // per-wave P [q][k]

    const int qrow0 = qt * BQ + w * 16;

    // ---- Q fragments (A-operand: row=l16, k=8*lq+j) ----
    bf16x8 qf[4];
    {
        const float* qp = Q + (size_t)(qrow0 + l16) * QSTR + h * HD + lq * 8;
        #pragma unroll
        for (int d0 = 0; d0 < 4; ++d0) {
            f32x4 a = *(const f32x4*)(qp + d0 * 32);
            f32x4 b = *(const f32x4*)(qp + d0 * 32 + 4);
            u32x4 t;
            t[0] = cvt_pk_bf16(a[0], a[1]); t[1] = cvt_pk_bf16(a[2], a[3]);
            t[2] = cvt_pk_bf16(b[0], b[1]); t[3] = cvt_pk_bf16(b[2], b[3]);
            qf[d0] = as_bf16x8(t);
        }
    }
    // all-ones B fragment for the P row-sum MFMA
    bf16x8 onesf;
    #pragma unroll
    for (int j = 0; j < 8; ++j) onesf[j] = (short)0x3f80;

    f32x4 acc[8];
    #pragma unroll
    for (int t = 0; t < 8; ++t) acc[t] = (f32x4){0.f, 0.f, 0.f, 0.f};
    float m_i[4] = {-1e30f, -1e30f, -1e30f, -1e30f};
    float l_i[4] = {0.f, 0.f, 0.f, 0.f};

    const int kv_end = qt * BQ + BQ;

    // ---- ALiBi far-tile skip (weight <= e^-33 vs diagonal) ----
    int kb_start = 0;
    {
        float thresh = (float)(qt * BQ) - 31.0f - 45.0f / slope;
        int t = (int)floorf(thresh);
        kb_start = (t < 0) ? 0 : (((t >> 5) + 1) << 5);
    }

    // ---- staging thread mapping ----
    const int sr  = tid >> 4, scc = tid & 15;         // K: rows sr, sr+16
    const int vd  = tid & 127, vrb = (tid >> 7) * 8;  // V: col d, 8 consecutive k
    const float* Kbase = K + (size_t)kvh * HD + scc * 8;
    const float* Vbase = V + (size_t)kvh * HD + vd;

    float kr[2][8], vr[2][8];

    auto load_regs = [&](int kb) {
        #pragma unroll
        for (int s = 0; s < 2; ++s) {
            const float* kp = Kbase + (size_t)(kb + sr + s * 16) * KSTR;
            *(f32x4*)&kr[s][0] = *(const f32x4*)kp;
            *(f32x4*)&kr[s][4] = *(const f32x4*)(kp + 4);
        }
        #pragma unroll
        for (int s = 0; s < 2; ++s)
            #pragma unroll
            for (int j = 0; j < 8; ++j)
                vr[s][j] = Vbase[(size_t)(kb + vrb + s * 16 + j) * KSTR];
    };

    auto store_tile = [&](int b) {
        #pragma unroll
        for (int s = 0; s < 2; ++s) {
            u32x4 t;
            t[0] = cvt_pk_bf16(kr[s][0], kr[s][1]);
            t[1] = cvt_pk_bf16(kr[s][2], kr[s][3]);
            t[2] = cvt_pk_bf16(kr[s][4], kr[s][5]);
            t[3] = cvt_pk_bf16(kr[s][6], kr[s][7]);
            *(u32x4*)&Ks[b][(sr + s * 16) * K_STRIDE + scc * 8] = t;
        }
        #pragma unroll
        for (int s = 0; s < 2; ++s) {
            u32x4 t;
            t[0] = cvt_pk_bf16(vr[s][0], vr[s][1]);
            t[1] = cvt_pk_bf16(vr[s][2], vr[s][3]);
            t[2] = cvt_pk_bf16(vr[s][4], vr[s][5]);
            t[3] = cvt_pk_bf16(vr[s][6], vr[s][7]);
            *(u32x4*)&VTs[b][vd * VT_STRIDE + vrb + s * 16] = t;
        }
    };

    // prologue: stage first tile into buffer 0
    load_regs(kb_start);
    store_tile(0);
    int cur = 0;

    for (int kb = kb_start; kb < kv_end; kb += BK) {
        // one barrier per tile; vmcnt NOT drained (prefetch spans barrier)
        asm volatile("s_waitcnt lgkmcnt(0)\n\ts_barrier" ::: "memory");

        const bool has_next = (kb + BK) < kv_end;
        if (has_next) load_regs(kb + BK);   // global loads in flight across compute

        const bool live = (kb <= qrow0 + 15) &&
                          (slope * (float)(qrow0 - kb - 31) < 45.0f);
        if (live) {
            const short* Kc = &Ks[cur][0];
            const short* Vc = &VTs[cur][0];

            // ---- QK^T ----
            f32x4 sc0 = (f32x4){0.f,0.f,0.f,0.f};
            f32x4 sc1 = (f32x4){0.f,0.f,0.f,0.f};
            #pragma unroll
            for (int d0 = 0; d0 < 4; ++d0) {
                bf16x8 kf0 = *(const bf16x8*)&Kc[l16 * K_STRIDE + d0 * 32 + lq * 8];
                bf16x8 kf1 = *(const bf16x8*)&Kc[(16 + l16) * K_STRIDE + d0 * 32 + lq * 8];
                sc0 = __builtin_amdgcn_mfma_f32_16x16x32_bf16(qf[d0], kf0, sc0, 0, 0, 0);
                sc1 = __builtin_amdgcn_mfma_f32_16x16x32_bf16(qf[d0], kf1, sc1, 0, 0, 0);
            }

            // ---- scale + ALiBi + causal ----
            float s0v[4], s1v[4], lm[4];
            bool need = false;
            #pragma unroll
            for (int i = 0; i < 4; ++i) {
                const int qrow = qrow0 + 4 * lq + i;
                const int kc0 = kb + l16;
                const int kc1 = kb + 16 + l16;
                float s0 = (kc0 > qrow) ? -1e30f
                         : sc0[i] * QK_SCALE + slope * (float)(kc0 - qrow);
                float s1 = (kc1 > qrow) ? -1e30f
                         : sc1[i] * QK_SCALE + slope * (float)(kc1 - qrow);
                s0v[i] = s0; s1v[i] = s1;
                lm[i] = fmaxf(s0, s1);
                need = need || (lm[i] > m_i[i] + 8.0f);
            }
            // ---- defer-max: shuffle-reduce + rescale only on growth (rare) ----
            if (__any(need)) {
                #pragma unroll
                for (int i = 0; i < 4; ++i) {
                    float rm = lm[i];
                    rm = fmaxf(rm, __shfl_xor(rm, 1));
                    rm = fmaxf(rm, __shfl_xor(rm, 2));
                    rm = fmaxf(rm, __shfl_xor(rm, 4));
                    rm = fmaxf(rm, __shfl_xor(rm, 8));
                    if (rm > m_i[i] + 8.0f) {
                        float alpha = exp2f((m_i[i] - rm) * LOG2E);
                        m_i[i] = rm;
                        l_i[i] *= alpha;
                        #pragma unroll
                        for (int t = 0; t < 8; ++t) acc[t][i] *= alpha;
                    }
                }
            }

            // ---- P = exp2(s - m), commit to bf16 via LDS ----
            short* PsW = &Ps[w][0];
            #pragma unroll
            for (int i = 0; i < 4; ++i) {
                float p0 = exp2f((s0v[i] - m_i[i]) * LOG2E);
                float p1 = exp2f((s1v[i] - m_i[i]) * LOG2E);
                PsW[(4 * lq + i) * P_STRIDE + l16]      = f2bf(p0);
                PsW[(4 * lq + i) * P_STRIDE + 16 + l16] = f2bf(p1);
            }
            asm volatile("s_waitcnt lgkmcnt(0)" ::: "memory");
            bf16x8 pf = *(const bf16x8*)&PsW[l16 * P_STRIDE + lq * 8];

            // ---- row-sum of P via ones-MFMA (replaces 16 shuffles) ----
            f32x4 sums = (f32x4){0.f,0.f,0.f,0.f};
            sums = __builtin_amdgcn_mfma_f32_16x16x32_bf16(pf, onesf, sums, 0, 0, 0);

            // ---- PV ----
            #pragma unroll
            for (int nt = 0; nt < 8; ++nt) {
                bf16x8 vf = *(const bf16x8*)&Vc[(nt * 16 + l16) * VT_STRIDE + lq * 8];
                acc[nt] = __builtin_amdgcn_mfma_f32_16x16x32_bf16(pf, vf, acc[nt], 0, 0, 0);
            }
            #pragma unroll
            for (int i = 0; i < 4; ++i) l_i[i] += sums[i];
        }

        if (has_next) store_tile(cur ^ 1);   // fill other buffer while others compute
        cur ^= 1;
    }

    // ---- epilogue ----
    #pragma unroll
    for (int i = 0; i < 4; ++i) {
        float rl = 1.0f / l_i[i];
        const size_t row = (size_t)(qrow0 + 4 * lq + i);
        float* op = O + row * QSTR + h * HD + l16;
        #pragma unroll
        for (int nt = 0; nt < 8; ++nt)
            op[nt * 16] = acc[nt][i] * rl;
    }
}

extern "C" void kernel_launch(void* const* d_in, const int* in_sizes, int n_in,
                              void* d_out, int out_size, void* d_ws, size_t ws_size,
                              hipStream_t stream) {
    const float* Q  = (const float*)d_in[0];
    const float* K  = (const float*)d_in[1];
    const float* V  = (const float*)d_in[2];
    const float* SL = (const float*)d_in[3];
    float* O = (float*)d_out;

    dim3 grid(NQT * NHEADS);
    dim3 block(256);
    attn_fwd<<<grid, block, 0, stream>>>(Q, K, V, SL, O);
}